// Round 8
// baseline (189.302 us; speedup 1.0000x reference)
//
#include <hip/hip_runtime.h>
#include <cmath>

#define N_NODES 4096
#define FIN     128
#define H_HEADS 8
#define FOUT    64
#define HF      512   // H*FOUT
#define CAP     256   // max neighbors; c ~ 83 +/- 9 -> 256 is ~19 sigma
#define GEMM_BLOCKS 1024   // 64 row-tiles x 16 col-tiles
#define ADJ_SPLIT 2        // blocks per adj row

typedef float  vf4 __attribute__((ext_vector_type(4)));
typedef float  vf2 __attribute__((ext_vector_type(2)));
typedef unsigned int vu4 __attribute__((ext_vector_type(4)));

__device__ __forceinline__ unsigned short f2bf(float f) {
    unsigned u = __float_as_uint(f);
    u += 0x7fff + ((u >> 16) & 1);          // round-to-nearest-even
    return (unsigned short)(u >> 16);
}

// ---------------------------------------------------------------------------
// K1: fused {GEMM tiles | adj stream+compact}. 256 threads/block.
//  - blocks [0,1024): C = x @ W^T -> proj(bf16)+scores / skip(fp32). BK=32.
//  - blocks [1024, 1024+8192): adj half-row stream. CACHED loads (L3 serves
//    part of adj - R7 FETCH=41MB < 64MB proved it), NT stores. Global
//    atomicAdd(&cnt[row]) merges the two halves' compaction.
// ---------------------------------------------------------------------------
__global__ __launch_bounds__(256) void k1_fused(
    const float* __restrict__ x, const float* __restrict__ Wp,
    const float* __restrict__ Ws, const float* __restrict__ a_src,
    const float* __restrict__ a_tgt, const float* __restrict__ adj,
    unsigned short* __restrict__ proj, float* __restrict__ skip,
    float* __restrict__ ssrc, float* __restrict__ stgt,
    int* __restrict__ cnt, int* __restrict__ idx,
    float* __restrict__ adj_out)
{
    __shared__ __align__(16) float smem[2 * 32 * 68];   // 17408 B
    const int bx = blockIdx.x;
    const int t  = threadIdx.x;

    if (bx < GEMM_BLOCKS) {
        // ---- GEMM tile ----
        float (*AsT)[68] = (float(*)[68])smem;            // [k][row]
        float (*BsT)[68] = (float(*)[68])(smem + 32 * 68);
        const int rb = (bx >> 4) * 64;
        const int cb = (bx & 15) * 64;
        const bool isP = (cb < HF);
        const float* Wbase = isP ? (Wp + cb * FIN) : (Ws + (cb - HF) * FIN);

        const int tx = t & 15;
        const int ty = t >> 4;
        float acc[4][4] = {{0.f}};

        for (int kb = 0; kb < FIN; kb += 32) {
            #pragma unroll
            for (int p = 0; p < 2; ++p) {
                int f4 = t + p * 256;        // 0..511
                int r  = f4 >> 3;            // 0..63
                int k4 = f4 & 7;             // 0..7
                float4 a = *(const float4*)(x + (size_t)(rb + r) * FIN + kb + k4 * 4);
                AsT[k4*4+0][r] = a.x; AsT[k4*4+1][r] = a.y;
                AsT[k4*4+2][r] = a.z; AsT[k4*4+3][r] = a.w;
                float4 b = *(const float4*)(Wbase + (size_t)r * FIN + kb + k4 * 4);
                BsT[k4*4+0][r] = b.x; BsT[k4*4+1][r] = b.y;
                BsT[k4*4+2][r] = b.z; BsT[k4*4+3][r] = b.w;
            }
            __syncthreads();
            #pragma unroll 8
            for (int kk = 0; kk < 32; ++kk) {
                float4 a = *(const float4*)&AsT[kk][ty * 4];
                float4 b = *(const float4*)&BsT[kk][tx * 4];
                acc[0][0] += a.x*b.x; acc[0][1] += a.x*b.y; acc[0][2] += a.x*b.z; acc[0][3] += a.x*b.w;
                acc[1][0] += a.y*b.x; acc[1][1] += a.y*b.y; acc[1][2] += a.y*b.z; acc[1][3] += a.y*b.w;
                acc[2][0] += a.z*b.x; acc[2][1] += a.z*b.y; acc[2][2] += a.z*b.z; acc[2][3] += a.z*b.w;
                acc[3][0] += a.w*b.x; acc[3][1] += a.w*b.y; acc[3][2] += a.w*b.z; acc[3][3] += a.w*b.w;
            }
            __syncthreads();
        }

        if (isP) {
            #pragma unroll
            for (int i = 0; i < 4; ++i) {
                ushort4 v;
                v.x = f2bf(acc[i][0]); v.y = f2bf(acc[i][1]);
                v.z = f2bf(acc[i][2]); v.w = f2bf(acc[i][3]);
                *(ushort4*)(proj + (size_t)(rb + ty*4 + i) * HF + cb + tx * 4) = v;
            }
            const int h = cb >> 6;
            const float as0 = a_src[cb + tx*4 + 0], as1 = a_src[cb + tx*4 + 1];
            const float as2 = a_src[cb + tx*4 + 2], as3 = a_src[cb + tx*4 + 3];
            const float at0 = a_tgt[cb + tx*4 + 0], at1 = a_tgt[cb + tx*4 + 1];
            const float at2 = a_tgt[cb + tx*4 + 2], at3 = a_tgt[cb + tx*4 + 3];
            #pragma unroll
            for (int i = 0; i < 4; ++i) {
                float ps = acc[i][0]*as0 + acc[i][1]*as1 + acc[i][2]*as2 + acc[i][3]*as3;
                float pt = acc[i][0]*at0 + acc[i][1]*at1 + acc[i][2]*at2 + acc[i][3]*at3;
                #pragma unroll
                for (int off = 1; off < 16; off <<= 1) {
                    ps += __shfl_xor(ps, off);
                    pt += __shfl_xor(pt, off);
                }
                if (tx == 0) {
                    int n = rb + ty*4 + i;
                    ssrc[n * H_HEADS + h] = ps;
                    stgt[n * H_HEADS + h] = pt;
                }
            }
        } else {
            #pragma unroll
            for (int i = 0; i < 4; ++i) {
                float4 v = make_float4(acc[i][0], acc[i][1], acc[i][2], acc[i][3]);
                *(float4*)(skip + (size_t)(rb + ty*4 + i) * HF + (cb - HF) + tx * 4) = v;
            }
        }
    } else {
        // ---- adj half-row stream + compact ----
        const int job  = bx - GEMM_BLOCKS;           // 0..8191
        const int i    = job >> 1;                   // row
        const int half = job & 1;                    // 0: cols[0,2048), 1: cols[2048,4096)
        const int lane = t & 63;
        const unsigned long long lt = (1ull << lane) - 1ull;
        const int base4 = half * 512;                // float4 offset of this half
        const vf4* arow = (const vf4*)(adj + (size_t)i * N_NODES) + base4;
        vf4*       aout = (vf4*)(adj_out + (size_t)i * N_NODES) + base4;
        int* rowidx = idx + i * CAP;
        #pragma unroll
        for (int it = 0; it < 2; ++it) {
            const int f4 = t + it * 256;             // 0..511 within half
            vf4 v = arow[f4];                        // CACHED load (L2/L3 can serve)
            __builtin_nontemporal_store(v, aout + f4);
            const int jb = ((base4 + f4) * 4) << 10; // byte offset of proj row (j*HF*2)
            const bool h0 = (v.x == 0.f), h1 = (v.y == 0.f), h2 = (v.z == 0.f), h3 = (v.w == 0.f);
            const unsigned long long b0 = __ballot(h0), b1 = __ballot(h1);
            const unsigned long long b2 = __ballot(h2), b3 = __ballot(h3);
            const int n0 = __popcll(b0), n1 = __popcll(b1), n2 = __popcll(b2);
            const int total = n0 + n1 + n2 + __popcll(b3);
            int base = 0;
            if (lane == 0 && total) base = atomicAdd(&cnt[i], total);
            base = __shfl(base, 0);
            if (h0) { int p = base + __popcll(b0 & lt);                if (p < CAP) rowidx[p] = jb;        }
            if (h1) { int p = base + n0 + __popcll(b1 & lt);           if (p < CAP) rowidx[p] = jb + 1024; }
            if (h2) { int p = base + n0 + n1 + __popcll(b2 & lt);      if (p < CAP) rowidx[p] = jb + 2048; }
            if (h3) { int p = base + n0 + n1 + n2 + __popcll(b3 & lt); if (p < CAP) rowidx[p] = jb + 3072; }
        }
    }
}

// ---------------------------------------------------------------------------
// K2: per-(row, head-half) {scores + softmax + bf16 PV gather + epilogue}.
// 2 blocks per row, 256 threads = 4 waves, wave w <-> head hb+w.
// launch_bounds(256,8): 8 blocks/CU. Gather batches 4 independent neighbors.
// ---------------------------------------------------------------------------
__global__ __launch_bounds__(256, 8) void att_kernel(
    const unsigned short* __restrict__ proj, const float* __restrict__ skip,
    const float* __restrict__ ssrc, const float* __restrict__ stgt,
    const float* __restrict__ bias, const int* __restrict__ cnt,
    const int* __restrict__ idx, float* __restrict__ out)
{
    __shared__ int   s_idx[CAP];
    __shared__ float sp[4][CAP];
    __shared__ float s_i[4];

    const int t    = threadIdx.x;
    const int i    = blockIdx.x >> 1;        // row
    const int hb   = (blockIdx.x & 1) * 4;   // head base: 0 or 4
    const int lane = t & 63;
    if (t < 4) s_i[t] = ssrc[i * H_HEADS + hb + t];
    int c = cnt[i]; if (c > CAP) c = CAP;    // >=1 (self loop)
    __syncthreads();

    // scores for 4 heads from the compact list (also stage idx into LDS)
    for (int k = t; k < c; k += 256) {
        const int off = idx[i * CAP + k];
        s_idx[k] = off;
        const float4 t0 = *(const float4*)((const char*)stgt + (off >> 5) + hb * 4);
        float e;
        e = s_i[0] + t0.x; sp[0][k] = (e > 0.f) ? e : 0.2f * e;
        e = s_i[1] + t0.y; sp[1][k] = (e > 0.f) ? e : 0.2f * e;
        e = s_i[2] + t0.z; sp[2][k] = (e > 0.f) ? e : 0.2f * e;
        e = s_i[3] + t0.w; sp[3][k] = (e > 0.f) ? e : 0.2f * e;
    }
    __syncthreads();

    // per-head softmax (wave w owns head hb+w; later stages read own-wave data)
    const int w = t >> 6;
    float m = -1e30f;
    for (int k = lane; k < c; k += 64) m = fmaxf(m, sp[w][k]);
    #pragma unroll
    for (int off = 32; off; off >>= 1) m = fmaxf(m, __shfl_xor(m, off));
    float l = 0.0f;
    for (int k = lane; k < c; k += 64) {
        float e = __expf(sp[w][k] - m);
        sp[w][k] = e;
        l += e;
    }
    #pragma unroll
    for (int off = 32; off; off >>= 1) l += __shfl_xor(l, off);
    const float inv = 1.0f / l;

    // bf16 gather: slot g handles neighbors k = g (mod 8); batch 4 per iter
    const int g  = lane >> 3;     // neighbor slot 0..7
    const int k8 = lane & 7;      // feature octet 0..7
    vf2 a2[4] = {{0.f, 0.f}, {0.f, 0.f}, {0.f, 0.f}, {0.f, 0.f}};
    const char* pbase = (const char*)proj + (hb + w) * FOUT * 2 + k8 * 16;
    int k = g;
    for (; k + 24 < c; k += 32) {
        const int o0 = s_idx[k], o1 = s_idx[k + 8], o2 = s_idx[k + 16], o3 = s_idx[k + 24];
        vu4 r0 = *(const vu4*)(pbase + o0);
        vu4 r1 = *(const vu4*)(pbase + o1);
        vu4 r2 = *(const vu4*)(pbase + o2);
        vu4 r3 = *(const vu4*)(pbase + o3);
        const float p0 = sp[w][k], p1 = sp[w][k + 8], p2 = sp[w][k + 16], p3 = sp[w][k + 24];
        const vf2 q0 = {p0, p0}, q1 = {p1, p1}, q2 = {p2, p2}, q3 = {p3, p3};
        a2[0] += q0 * (vf2){ __uint_as_float(r0.x << 16), __uint_as_float(r0.x & 0xffff0000u) };
        a2[1] += q0 * (vf2){ __uint_as_float(r0.y << 16), __uint_as_float(r0.y & 0xffff0000u) };
        a2[2] += q0 * (vf2){ __uint_as_float(r0.z << 16), __uint_as_float(r0.z & 0xffff0000u) };
        a2[3] += q0 * (vf2){ __uint_as_float(r0.w << 16), __uint_as_float(r0.w & 0xffff0000u) };
        a2[0] += q1 * (vf2){ __uint_as_float(r1.x << 16), __uint_as_float(r1.x & 0xffff0000u) };
        a2[1] += q1 * (vf2){ __uint_as_float(r1.y << 16), __uint_as_float(r1.y & 0xffff0000u) };
        a2[2] += q1 * (vf2){ __uint_as_float(r1.z << 16), __uint_as_float(r1.z & 0xffff0000u) };
        a2[3] += q1 * (vf2){ __uint_as_float(r1.w << 16), __uint_as_float(r1.w & 0xffff0000u) };
        a2[0] += q2 * (vf2){ __uint_as_float(r2.x << 16), __uint_as_float(r2.x & 0xffff0000u) };
        a2[1] += q2 * (vf2){ __uint_as_float(r2.y << 16), __uint_as_float(r2.y & 0xffff0000u) };
        a2[2] += q2 * (vf2){ __uint_as_float(r2.z << 16), __uint_as_float(r2.z & 0xffff0000u) };
        a2[3] += q2 * (vf2){ __uint_as_float(r2.w << 16), __uint_as_float(r2.w & 0xffff0000u) };
        a2[0] += q3 * (vf2){ __uint_as_float(r3.x << 16), __uint_as_float(r3.x & 0xffff0000u) };
        a2[1] += q3 * (vf2){ __uint_as_float(r3.y << 16), __uint_as_float(r3.y & 0xffff0000u) };
        a2[2] += q3 * (vf2){ __uint_as_float(r3.z << 16), __uint_as_float(r3.z & 0xffff0000u) };
        a2[3] += q3 * (vf2){ __uint_as_float(r3.w << 16), __uint_as_float(r3.w & 0xffff0000u) };
    }
    for (; k < c; k += 8) {
        const int   off = s_idx[k];
        const float p   = sp[w][k];
        const vf2   p2  = {p, p};
        vu4 raw = *(const vu4*)(pbase + off);
        a2[0] += p2 * (vf2){ __uint_as_float(raw.x << 16), __uint_as_float(raw.x & 0xffff0000u) };
        a2[1] += p2 * (vf2){ __uint_as_float(raw.y << 16), __uint_as_float(raw.y & 0xffff0000u) };
        a2[2] += p2 * (vf2){ __uint_as_float(raw.z << 16), __uint_as_float(raw.z & 0xffff0000u) };
        a2[3] += p2 * (vf2){ __uint_as_float(raw.w << 16), __uint_as_float(raw.w & 0xffff0000u) };
    }
    float a8[8] = {a2[0].x, a2[0].y, a2[1].x, a2[1].y,
                   a2[2].x, a2[2].y, a2[3].x, a2[3].y};
    #pragma unroll
    for (int off = 8; off < 64; off <<= 1) {
        #pragma unroll
        for (int q = 0; q < 8; ++q) a8[q] += __shfl_xor(a8[q], off);
    }
    if (g == 0) {
        const int o = (hb + w) * FOUT + k8 * 8;
        const float* sk = skip + (size_t)i * HF + o;
        const float* bs = bias + o;
        float r[8];
        #pragma unroll
        for (int q = 0; q < 8; ++q) {
            float v = a8[q] * inv + sk[q] + bs[q];
            r[q] = (v > 0.f) ? v : expm1f(v);   // ELU(alpha=1)
        }
        *(float4*)(out + (size_t)i * HF + o)     = make_float4(r[0], r[1], r[2], r[3]);
        *(float4*)(out + (size_t)i * HF + o + 4) = make_float4(r[4], r[5], r[6], r[7]);
    }
}

// ---------------------------------------------------------------------------
extern "C" void kernel_launch(void* const* d_in, const int* in_sizes, int n_in,
                              void* d_out, int out_size, void* d_ws, size_t ws_size,
                              hipStream_t stream)
{
    const float* x     = (const float*)d_in[0];   // [1,4096,128]
    const float* adj   = (const float*)d_in[1];   // [4096,4096]
    const float* Wp    = (const float*)d_in[2];   // [512,128]
    const float* a_src = (const float*)d_in[3];   // [1,8,64]
    const float* a_tgt = (const float*)d_in[4];   // [1,8,64]
    const float* Ws    = (const float*)d_in[5];   // [512,128]
    const float* bias  = (const float*)d_in[6];   // [512]

    float* out     = (float*)d_out;                      // output 0: [4096*512]
    float* adj_out = out + (size_t)N_NODES * HF;         // output 1: [4096*4096]

    // ws layout (8.27 MB): proj bf16 4MB | ssrc 128KB | stgt 128KB |
    //                      cnt 16KB | idx 4MB
    unsigned short* proj = (unsigned short*)d_ws;
    float* ssrc = (float*)((char*)d_ws + (size_t)N_NODES * HF * 2);
    float* stgt = ssrc + (size_t)N_NODES * H_HEADS;
    int*   cnt  = (int*)(stgt + (size_t)N_NODES * H_HEADS);
    int*   idxb = cnt + N_NODES;
    float* skip = out;   // staged in d_out; K2 reads row i before overwriting it

    hipMemsetAsync(cnt, 0, N_NODES * sizeof(int), stream);
    k1_fused<<<GEMM_BLOCKS + ADJ_SPLIT * N_NODES, 256, 0, stream>>>(
        x, Wp, Ws, a_src, a_tgt, adj, proj, skip, ssrc, stgt, cnt, idxb, adj_out);
    att_kernel<<<2 * N_NODES, 256, 0, stream>>>(proj, skip, ssrc, stgt, bias,
                                                cnt, idxb, out);
}

// Round 9
// 183.943 us; speedup vs baseline: 1.0291x; 1.0291x over previous
//
#include <hip/hip_runtime.h>
#include <cmath>

#define N_NODES 4096
#define FIN     128
#define H_HEADS 8
#define FOUT    64
#define HF      512   // H*FOUT
#define CAP     256   // max neighbors; c ~ 83 +/- 9 -> 256 is ~19 sigma
#define GEMM_BLOCKS 1024   // 64 row-tiles x 16 col-tiles

typedef float  vf4 __attribute__((ext_vector_type(4)));
typedef float  vf2 __attribute__((ext_vector_type(2)));
typedef unsigned int vu4 __attribute__((ext_vector_type(4)));

__device__ __forceinline__ unsigned short f2bf(float f) {
    unsigned u = __float_as_uint(f);
    u += 0x7fff + ((u >> 16) & 1);          // round-to-nearest-even
    return (unsigned short)(u >> 16);
}

// ---------------------------------------------------------------------------
// K1: fused {GEMM tiles | adj stream+compact}. 256 threads/block.
//  - blocks [0,1024): C = x @ W^T -> proj(bf16)+scores / skip(fp32). BK=32.
//  - blocks [1024,5120): one adj row per block. REGULAR loads+stores (stores
//    ack at L2, not HBM -> block retires without an HBM drain; NT stores in
//    R1-R8 forced a full HBM round-trip per block, capping the stream at
//    ~2.4 TB/s). LDS count, no global atomics, no memset prepass.
// ---------------------------------------------------------------------------
__global__ __launch_bounds__(256) void k1_fused(
    const float* __restrict__ x, const float* __restrict__ Wp,
    const float* __restrict__ Ws, const float* __restrict__ a_src,
    const float* __restrict__ a_tgt, const float* __restrict__ adj,
    unsigned short* __restrict__ proj, float* __restrict__ skip,
    float* __restrict__ ssrc, float* __restrict__ stgt,
    int* __restrict__ cnt, int* __restrict__ idx,
    float* __restrict__ adj_out)
{
    __shared__ __align__(16) float smem[2 * 32 * 68];   // 17408 B
    const int bx = blockIdx.x;
    const int t  = threadIdx.x;

    if (bx < GEMM_BLOCKS) {
        // ---- GEMM tile ----
        float (*AsT)[68] = (float(*)[68])smem;            // [k][row]
        float (*BsT)[68] = (float(*)[68])(smem + 32 * 68);
        const int rb = (bx >> 4) * 64;
        const int cb = (bx & 15) * 64;
        const bool isP = (cb < HF);
        const float* Wbase = isP ? (Wp + cb * FIN) : (Ws + (cb - HF) * FIN);

        const int tx = t & 15;
        const int ty = t >> 4;
        float acc[4][4] = {{0.f}};

        for (int kb = 0; kb < FIN; kb += 32) {
            #pragma unroll
            for (int p = 0; p < 2; ++p) {
                int f4 = t + p * 256;        // 0..511
                int r  = f4 >> 3;            // 0..63
                int k4 = f4 & 7;             // 0..7
                float4 a = *(const float4*)(x + (size_t)(rb + r) * FIN + kb + k4 * 4);
                AsT[k4*4+0][r] = a.x; AsT[k4*4+1][r] = a.y;
                AsT[k4*4+2][r] = a.z; AsT[k4*4+3][r] = a.w;
                float4 b = *(const float4*)(Wbase + (size_t)r * FIN + kb + k4 * 4);
                BsT[k4*4+0][r] = b.x; BsT[k4*4+1][r] = b.y;
                BsT[k4*4+2][r] = b.z; BsT[k4*4+3][r] = b.w;
            }
            __syncthreads();
            #pragma unroll 8
            for (int kk = 0; kk < 32; ++kk) {
                float4 a = *(const float4*)&AsT[kk][ty * 4];
                float4 b = *(const float4*)&BsT[kk][tx * 4];
                acc[0][0] += a.x*b.x; acc[0][1] += a.x*b.y; acc[0][2] += a.x*b.z; acc[0][3] += a.x*b.w;
                acc[1][0] += a.y*b.x; acc[1][1] += a.y*b.y; acc[1][2] += a.y*b.z; acc[1][3] += a.y*b.w;
                acc[2][0] += a.z*b.x; acc[2][1] += a.z*b.y; acc[2][2] += a.z*b.z; acc[2][3] += a.z*b.w;
                acc[3][0] += a.w*b.x; acc[3][1] += a.w*b.y; acc[3][2] += a.w*b.z; acc[3][3] += a.w*b.w;
            }
            __syncthreads();
        }

        if (isP) {
            #pragma unroll
            for (int i = 0; i < 4; ++i) {
                ushort4 v;
                v.x = f2bf(acc[i][0]); v.y = f2bf(acc[i][1]);
                v.z = f2bf(acc[i][2]); v.w = f2bf(acc[i][3]);
                *(ushort4*)(proj + (size_t)(rb + ty*4 + i) * HF + cb + tx * 4) = v;
            }
            const int h = cb >> 6;
            const float as0 = a_src[cb + tx*4 + 0], as1 = a_src[cb + tx*4 + 1];
            const float as2 = a_src[cb + tx*4 + 2], as3 = a_src[cb + tx*4 + 3];
            const float at0 = a_tgt[cb + tx*4 + 0], at1 = a_tgt[cb + tx*4 + 1];
            const float at2 = a_tgt[cb + tx*4 + 2], at3 = a_tgt[cb + tx*4 + 3];
            #pragma unroll
            for (int i = 0; i < 4; ++i) {
                float ps = acc[i][0]*as0 + acc[i][1]*as1 + acc[i][2]*as2 + acc[i][3]*as3;
                float pt = acc[i][0]*at0 + acc[i][1]*at1 + acc[i][2]*at2 + acc[i][3]*at3;
                #pragma unroll
                for (int off = 1; off < 16; off <<= 1) {
                    ps += __shfl_xor(ps, off);
                    pt += __shfl_xor(pt, off);
                }
                if (tx == 0) {
                    int n = rb + ty*4 + i;
                    ssrc[n * H_HEADS + h] = ps;
                    stgt[n * H_HEADS + h] = pt;
                }
            }
        } else {
            #pragma unroll
            for (int i = 0; i < 4; ++i) {
                float4 v = make_float4(acc[i][0], acc[i][1], acc[i][2], acc[i][3]);
                *(float4*)(skip + (size_t)(rb + ty*4 + i) * HF + (cb - HF) + tx * 4) = v;
            }
        }
    } else {
        // ---- adj stream + compact, one row per block, LDS count ----
        __shared__ int lcnt;
        const int i    = bx - GEMM_BLOCKS;
        const int lane = t & 63;
        if (t == 0) lcnt = 0;
        __syncthreads();
        const unsigned long long lt = (1ull << lane) - 1ull;
        const vf4* arow = (const vf4*)(adj + (size_t)i * N_NODES);
        vf4*       aout = (vf4*)(adj_out + (size_t)i * N_NODES);
        int* rowidx = idx + i * CAP;
        #pragma unroll
        for (int it = 0; it < 4; ++it) {
            const int f4 = t + it * 256;     // 0..1023
            vf4 v = arow[f4];                // regular load (L2/L3 can serve)
            aout[f4] = v;                    // regular store (acks at L2)
            const int jb = (f4 * 4) << 10;   // byte offset of proj row (j*HF*2)
            const bool h0 = (v.x == 0.f), h1 = (v.y == 0.f), h2 = (v.z == 0.f), h3 = (v.w == 0.f);
            const unsigned long long b0 = __ballot(h0), b1 = __ballot(h1);
            const unsigned long long b2 = __ballot(h2), b3 = __ballot(h3);
            const int n0 = __popcll(b0), n1 = __popcll(b1), n2 = __popcll(b2);
            const int total = n0 + n1 + n2 + __popcll(b3);
            int base = 0;
            if (lane == 0 && total) base = atomicAdd(&lcnt, total);
            base = __shfl(base, 0);
            if (h0) { int p = base + __popcll(b0 & lt);                if (p < CAP) rowidx[p] = jb;        }
            if (h1) { int p = base + n0 + __popcll(b1 & lt);           if (p < CAP) rowidx[p] = jb + 1024; }
            if (h2) { int p = base + n0 + n1 + __popcll(b2 & lt);      if (p < CAP) rowidx[p] = jb + 2048; }
            if (h3) { int p = base + n0 + n1 + n2 + __popcll(b3 & lt); if (p < CAP) rowidx[p] = jb + 3072; }
        }
        __syncthreads();
        if (t == 0) cnt[i] = lcnt;
    }
}

// ---------------------------------------------------------------------------
// K2: per-(row, head-half) {scores + softmax + bf16 PV gather + epilogue}.
// 2 blocks per row, 256 threads = 4 waves, wave w <-> head hb+w.
// launch_bounds(256,8): 8 blocks/CU. Gather batches 4 independent neighbors.
// ---------------------------------------------------------------------------
__global__ __launch_bounds__(256, 8) void att_kernel(
    const unsigned short* __restrict__ proj, const float* __restrict__ skip,
    const float* __restrict__ ssrc, const float* __restrict__ stgt,
    const float* __restrict__ bias, const int* __restrict__ cnt,
    const int* __restrict__ idx, float* __restrict__ out)
{
    __shared__ int   s_idx[CAP];
    __shared__ float sp[4][CAP];
    __shared__ float s_i[4];

    const int t    = threadIdx.x;
    const int i    = blockIdx.x >> 1;        // row
    const int hb   = (blockIdx.x & 1) * 4;   // head base: 0 or 4
    const int lane = t & 63;
    if (t < 4) s_i[t] = ssrc[i * H_HEADS + hb + t];
    int c = cnt[i]; if (c > CAP) c = CAP;    // >=1 (self loop)
    __syncthreads();

    // scores for 4 heads from the compact list (also stage idx into LDS)
    for (int k = t; k < c; k += 256) {
        const int off = idx[i * CAP + k];
        s_idx[k] = off;
        const float4 t0 = *(const float4*)((const char*)stgt + (off >> 5) + hb * 4);
        float e;
        e = s_i[0] + t0.x; sp[0][k] = (e > 0.f) ? e : 0.2f * e;
        e = s_i[1] + t0.y; sp[1][k] = (e > 0.f) ? e : 0.2f * e;
        e = s_i[2] + t0.z; sp[2][k] = (e > 0.f) ? e : 0.2f * e;
        e = s_i[3] + t0.w; sp[3][k] = (e > 0.f) ? e : 0.2f * e;
    }
    __syncthreads();

    // per-head softmax (wave w owns head hb+w; later stages read own-wave data)
    const int w = t >> 6;
    float m = -1e30f;
    for (int k = lane; k < c; k += 64) m = fmaxf(m, sp[w][k]);
    #pragma unroll
    for (int off = 32; off; off >>= 1) m = fmaxf(m, __shfl_xor(m, off));
    float l = 0.0f;
    for (int k = lane; k < c; k += 64) {
        float e = __expf(sp[w][k] - m);
        sp[w][k] = e;
        l += e;
    }
    #pragma unroll
    for (int off = 32; off; off >>= 1) l += __shfl_xor(l, off);
    const float inv = 1.0f / l;

    // bf16 gather: slot g handles neighbors k = g (mod 8); batch 4 per iter
    const int g  = lane >> 3;     // neighbor slot 0..7
    const int k8 = lane & 7;      // feature octet 0..7
    vf2 a2[4] = {{0.f, 0.f}, {0.f, 0.f}, {0.f, 0.f}, {0.f, 0.f}};
    const char* pbase = (const char*)proj + (hb + w) * FOUT * 2 + k8 * 16;
    int k = g;
    for (; k + 24 < c; k += 32) {
        const int o0 = s_idx[k], o1 = s_idx[k + 8], o2 = s_idx[k + 16], o3 = s_idx[k + 24];
        vu4 r0 = *(const vu4*)(pbase + o0);
        vu4 r1 = *(const vu4*)(pbase + o1);
        vu4 r2 = *(const vu4*)(pbase + o2);
        vu4 r3 = *(const vu4*)(pbase + o3);
        const float p0 = sp[w][k], p1 = sp[w][k + 8], p2 = sp[w][k + 16], p3 = sp[w][k + 24];
        const vf2 q0 = {p0, p0}, q1 = {p1, p1}, q2 = {p2, p2}, q3 = {p3, p3};
        a2[0] += q0 * (vf2){ __uint_as_float(r0.x << 16), __uint_as_float(r0.x & 0xffff0000u) };
        a2[1] += q0 * (vf2){ __uint_as_float(r0.y << 16), __uint_as_float(r0.y & 0xffff0000u) };
        a2[2] += q0 * (vf2){ __uint_as_float(r0.z << 16), __uint_as_float(r0.z & 0xffff0000u) };
        a2[3] += q0 * (vf2){ __uint_as_float(r0.w << 16), __uint_as_float(r0.w & 0xffff0000u) };
        a2[0] += q1 * (vf2){ __uint_as_float(r1.x << 16), __uint_as_float(r1.x & 0xffff0000u) };
        a2[1] += q1 * (vf2){ __uint_as_float(r1.y << 16), __uint_as_float(r1.y & 0xffff0000u) };
        a2[2] += q1 * (vf2){ __uint_as_float(r1.z << 16), __uint_as_float(r1.z & 0xffff0000u) };
        a2[3] += q1 * (vf2){ __uint_as_float(r1.w << 16), __uint_as_float(r1.w & 0xffff0000u) };
        a2[0] += q2 * (vf2){ __uint_as_float(r2.x << 16), __uint_as_float(r2.x & 0xffff0000u) };
        a2[1] += q2 * (vf2){ __uint_as_float(r2.y << 16), __uint_as_float(r2.y & 0xffff0000u) };
        a2[2] += q2 * (vf2){ __uint_as_float(r2.z << 16), __uint_as_float(r2.z & 0xffff0000u) };
        a2[3] += q2 * (vf2){ __uint_as_float(r2.w << 16), __uint_as_float(r2.w & 0xffff0000u) };
        a2[0] += q3 * (vf2){ __uint_as_float(r3.x << 16), __uint_as_float(r3.x & 0xffff0000u) };
        a2[1] += q3 * (vf2){ __uint_as_float(r3.y << 16), __uint_as_float(r3.y & 0xffff0000u) };
        a2[2] += q3 * (vf2){ __uint_as_float(r3.z << 16), __uint_as_float(r3.z & 0xffff0000u) };
        a2[3] += q3 * (vf2){ __uint_as_float(r3.w << 16), __uint_as_float(r3.w & 0xffff0000u) };
    }
    for (; k < c; k += 8) {
        const int   off = s_idx[k];
        const float p   = sp[w][k];
        const vf2   p2  = {p, p};
        vu4 raw = *(const vu4*)(pbase + off);
        a2[0] += p2 * (vf2){ __uint_as_float(raw.x << 16), __uint_as_float(raw.x & 0xffff0000u) };
        a2[1] += p2 * (vf2){ __uint_as_float(raw.y << 16), __uint_as_float(raw.y & 0xffff0000u) };
        a2[2] += p2 * (vf2){ __uint_as_float(raw.z << 16), __uint_as_float(raw.z & 0xffff0000u) };
        a2[3] += p2 * (vf2){ __uint_as_float(raw.w << 16), __uint_as_float(raw.w & 0xffff0000u) };
    }
    float a8[8] = {a2[0].x, a2[0].y, a2[1].x, a2[1].y,
                   a2[2].x, a2[2].y, a2[3].x, a2[3].y};
    #pragma unroll
    for (int off = 8; off < 64; off <<= 1) {
        #pragma unroll
        for (int q = 0; q < 8; ++q) a8[q] += __shfl_xor(a8[q], off);
    }
    if (g == 0) {
        const int o = (hb + w) * FOUT + k8 * 8;
        const float* sk = skip + (size_t)i * HF + o;
        const float* bs = bias + o;
        float r[8];
        #pragma unroll
        for (int q = 0; q < 8; ++q) {
            float v = a8[q] * inv + sk[q] + bs[q];
            r[q] = (v > 0.f) ? v : expm1f(v);   // ELU(alpha=1)
        }
        *(float4*)(out + (size_t)i * HF + o)     = make_float4(r[0], r[1], r[2], r[3]);
        *(float4*)(out + (size_t)i * HF + o + 4) = make_float4(r[4], r[5], r[6], r[7]);
    }
}

// ---------------------------------------------------------------------------
extern "C" void kernel_launch(void* const* d_in, const int* in_sizes, int n_in,
                              void* d_out, int out_size, void* d_ws, size_t ws_size,
                              hipStream_t stream)
{
    const float* x     = (const float*)d_in[0];   // [1,4096,128]
    const float* adj   = (const float*)d_in[1];   // [4096,4096]
    const float* Wp    = (const float*)d_in[2];   // [512,128]
    const float* a_src = (const float*)d_in[3];   // [1,8,64]
    const float* a_tgt = (const float*)d_in[4];   // [1,8,64]
    const float* Ws    = (const float*)d_in[5];   // [512,128]
    const float* bias  = (const float*)d_in[6];   // [512]

    float* out     = (float*)d_out;                      // output 0: [4096*512]
    float* adj_out = out + (size_t)N_NODES * HF;         // output 1: [4096*4096]

    // ws layout (8.27 MB): proj bf16 4MB | ssrc 128KB | stgt 128KB |
    //                      cnt 16KB | idx 4MB
    unsigned short* proj = (unsigned short*)d_ws;
    float* ssrc = (float*)((char*)d_ws + (size_t)N_NODES * HF * 2);
    float* stgt = ssrc + (size_t)N_NODES * H_HEADS;
    int*   cnt  = (int*)(stgt + (size_t)N_NODES * H_HEADS);
    int*   idxb = cnt + N_NODES;
    float* skip = out;   // staged in d_out; K2 reads row i before overwriting it

    k1_fused<<<GEMM_BLOCKS + N_NODES, 256, 0, stream>>>(
        x, Wp, Ws, a_src, a_tgt, adj, proj, skip, ssrc, stgt, cnt, idxb, adj_out);
    att_kernel<<<2 * N_NODES, 256, 0, stream>>>(proj, skip, ssrc, stgt, bias,
                                                cnt, idxb, out);
}